// Round 3
// baseline (193.651 us; speedup 1.0000x reference)
//
#include <hip/hip_runtime.h>
#include <hip/hip_bf16.h>

// Problem constants
constexpr int Dd = 1024;           // feature dim
constexpr int Tt = 2048;           // sequence length
constexpr int Bb = 4;              // batch
constexpr int Rr = Bb * Tt;        // GEMM rows = 8192
constexpr int NCHUNK = 32;         // scan chunks
constexpr int CLEN = Tt / NCHUNK;  // 64 steps per chunk
constexpr int SCAN_BLOCKS = (Bb * NCHUNK * Dd) / 256;  // 512
constexpr int WB_BLOCKS = 16;      // W-builder blocks (64 rows each)

typedef __attribute__((ext_vector_type(4))) float f32x4;
typedef __attribute__((ext_vector_type(8))) short bf16x8;

__device__ __forceinline__ float sigmoidf_(float v) {
    return 1.0f / (1.0f + expf(-v));
}

__device__ __forceinline__ void async16(const void* g, void* l) {
    __builtin_amdgcn_global_load_lds(
        (const __attribute__((address_space(1))) unsigned int*)g,
        (__attribute__((address_space(3))) unsigned int*)l,
        16, 0, 0);
}

// ---------------------------------------------------------------------------
// Kernel 1 (fused): blocks [0,512) local EMA scan -> bf16 xs + fp32 endv;
// blocks [512,528) build Wt (each computes circulant c redundantly in LDS,
// then writes a 64-row slice). W-build overlaps the scan.
// grid 528 x 256
__global__ void k_pre(const float* __restrict__ x,
                      const float* __restrict__ bind,
                      const float* __restrict__ unbind,
                      const float* __restrict__ decay,
                      __hip_bfloat16* __restrict__ xs,
                      float* __restrict__ endv,
                      __hip_bfloat16* __restrict__ wt) {
    __shared__ float sb[Dd];
    __shared__ float su[Dd];
    __shared__ float sc[Dd];

    const int tid = threadIdx.x;
    if (blockIdx.x < SCAN_BLOCKS) {
        // ---- local scan: one thread per (b,chunk,i) column ----
        int idx = blockIdx.x * 256 + tid;
        int i = idx & (Dd - 1);
        int chunk = (idx >> 10) & (NCHUNK - 1);
        int b = idx >> 15;
        float dd = sigmoidf_(decay[0]);
        size_t base = ((size_t)b * Tt + (size_t)chunk * CLEN) * Dd + i;
        float h = 0.f;
        #pragma unroll 8
        for (int t = 0; t < CLEN; ++t) {
            h = fmaf(dd, h, x[base + (size_t)t * Dd]);
            xs[base + (size_t)t * Dd] = __float2bfloat16(h);
        }
        endv[idx] = h;
    } else {
        // ---- W build: c[n] = sum_m unbind[m]*bind[(m+n)%D] in LDS, then
        //      Wt[n][k] = bf16(c[(n-k) mod D]) for 64 rows ----
        for (int j = tid; j < Dd; j += 256) { sb[j] = bind[j]; su[j] = unbind[j]; }
        __syncthreads();
        #pragma unroll
        for (int r = 0; r < 4; ++r) {
            int n = tid + r * 256;
            float acc = 0.f;
            #pragma unroll 8
            for (int m = 0; m < Dd; ++m)
                acc = fmaf(su[m], sb[(m + n) & (Dd - 1)], acc);
            sc[n] = acc;
        }
        __syncthreads();
        const int n0 = (int)(blockIdx.x - SCAN_BLOCKS) * 64;
        for (int g = tid; g < 64 * 128; g += 256) {
            int row = g >> 7;
            int k0 = (g & 127) * 8;
            int n = n0 + row;
            bf16x8 v;
            #pragma unroll
            for (int j = 0; j < 8; ++j) {
                union { __hip_bfloat16 b; short s; } u;
                u.b = __float2bfloat16(sc[(n - (k0 + j)) & (Dd - 1)]);
                v[j] = u.s;
            }
            *(bf16x8*)&wt[(size_t)n * Dd + k0] = v;
        }
    }
}

// ---------------------------------------------------------------------------
// Kernel 2: carry fixup in place. Thread per (b,chunk,i-pair):
// carry = sum_{c'<chunk} dL^{chunk-1-c'} endv[b][c'][i];  (uniform trip count)
// xs[b][chunk*64+t][i] += d^{t+1} * carry
// grid 256 x 256
__global__ void k_fix(const float* __restrict__ endv,
                      const float* __restrict__ decay,
                      __hip_bfloat16* __restrict__ xs) {
    int idx = blockIdx.x * 256 + threadIdx.x;
    int i2 = idx & 511;               // pair index
    int i = i2 * 2;
    int chunk = (idx >> 9) & (NCHUNK - 1);   // uniform within block
    int b = idx >> 14;
    if (chunk == 0) return;           // carry is zero, xs unchanged
    float dd = sigmoidf_(decay[0]);
    float dL = powf(dd, (float)CLEN);
    float c0 = 0.f, c1 = 0.f;
    for (int c = 0; c < chunk; ++c) {
        const float* e = endv + ((size_t)b * NCHUNK + c) * Dd + i;
        c0 = fmaf(dL, c0, e[0]);
        c1 = fmaf(dL, c1, e[1]);
    }
    float scale = dd;
    size_t base = ((size_t)b * Tt + (size_t)chunk * CLEN) * Dd + i;
    #pragma unroll 8
    for (int t = 0; t < CLEN; ++t) {
        union { ushort2 u; struct { __hip_bfloat16 a, b; } h; } p;
        p.u = *(const ushort2*)&xs[base + (size_t)t * Dd];
        float a0 = __bfloat162float(p.h.a) + scale * c0;
        float a1 = __bfloat162float(p.h.b) + scale * c1;
        p.h.a = __float2bfloat16(a0);
        p.h.b = __float2bfloat16(a1);
        *(ushort2*)&xs[base + (size_t)t * Dd] = p.u;
        scale *= dd;
    }
}

// ---------------------------------------------------------------------------
// Kernel 3: out[r][n] = x[r][n] + gate * sum_k xs[r][k] * Wt[n][k]
// 128x128 tile, BK=32, 4 waves 2x2, 16x16x32 bf16 MFMA, async LDS staging.
// grid (64, 8) x 256
__global__ __launch_bounds__(256) void k_gemm(
    const __hip_bfloat16* __restrict__ A,   // [R][D] bf16 (scanned x)
    const __hip_bfloat16* __restrict__ Wt,  // [D][D] bf16, Wt[n][k]
    const float* __restrict__ x,            // [R][D] fp32
    const float* __restrict__ gate,         // [1]
    float* __restrict__ out)                // [R][D] fp32
{
    __shared__ __align__(16) __hip_bfloat16 sA[128 * 32];
    __shared__ __align__(16) __hip_bfloat16 sB[128 * 32];

    const int tid = threadIdx.x;
    const int wave = tid >> 6;
    const int lane = tid & 63;
    const int tile_m = blockIdx.x * 128;
    const int tile_n = blockIdx.y * 128;
    const int wm = (wave & 1) * 64;
    const int wn = (wave >> 1) * 64;

    f32x4 acc[4][4];
    #pragma unroll
    for (int i = 0; i < 4; ++i)
        #pragma unroll
        for (int j = 0; j < 4; ++j)
            acc[i][j] = (f32x4){0.f, 0.f, 0.f, 0.f};

    const int srow = lane >> 2;
    const int skk  = (lane & 3) * 8;
    const int fr = lane & 15;
    const int fk = (lane >> 4) * 8;

    for (int k0 = 0; k0 < Dd; k0 += 32) {
        __syncthreads();
        #pragma unroll
        for (int j = 0; j < 2; ++j) {
            const int row = wave * 32 + j * 16;  // wave-uniform
            async16(A  + (size_t)(tile_m + row + srow) * Dd + k0 + skk, &sA[row * 32]);
            async16(Wt + (size_t)(tile_n + row + srow) * Dd + k0 + skk, &sB[row * 32]);
        }
        __syncthreads();

        bf16x8 af[4], bfr[4];
        #pragma unroll
        for (int mt = 0; mt < 4; ++mt)
            af[mt] = *(const bf16x8*)&sA[(wm + mt * 16 + fr) * 32 + fk];
        #pragma unroll
        for (int nt = 0; nt < 4; ++nt)
            bfr[nt] = *(const bf16x8*)&sB[(wn + nt * 16 + fr) * 32 + fk];

        #pragma unroll
        for (int mt = 0; mt < 4; ++mt)
            #pragma unroll
            for (int nt = 0; nt < 4; ++nt)
                acc[mt][nt] = __builtin_amdgcn_mfma_f32_16x16x32_bf16(
                    af[mt], bfr[nt], acc[mt][nt], 0, 0, 0);
    }

    const float g = gate[0];
    #pragma unroll
    for (int mt = 0; mt < 4; ++mt) {
        const int row0 = tile_m + wm + mt * 16 + (lane >> 4) * 4;
        #pragma unroll
        for (int nt = 0; nt < 4; ++nt) {
            const int col = tile_n + wn + nt * 16 + (lane & 15);
            #pragma unroll
            for (int gg = 0; gg < 4; ++gg) {
                const size_t off = (size_t)(row0 + gg) * Dd + col;
                out[off] = fmaf(g, acc[mt][nt][gg], x[off]);
            }
        }
    }
}

// ---------------------------------------------------------------------------
extern "C" void kernel_launch(void* const* d_in, const int* in_sizes, int n_in,
                              void* d_out, int out_size, void* d_ws, size_t ws_size,
                              hipStream_t stream) {
    const float* x      = (const float*)d_in[0];
    const float* bind   = (const float*)d_in[1];
    const float* unbind = (const float*)d_in[2];
    const float* gate   = (const float*)d_in[3];
    const float* decay  = (const float*)d_in[4];
    float* out = (float*)d_out;

    // workspace layout (~19.3 MB)
    char* ws = (char*)d_ws;
    __hip_bfloat16* wt = (__hip_bfloat16*)ws;                            // 2 MB
    __hip_bfloat16* xs = (__hip_bfloat16*)(ws + (size_t)Dd * Dd * 2);    // 16.8 MB
    float* endv = (float*)(ws + (size_t)Dd * Dd * 2 + (size_t)Rr * Dd * 2);  // 512 KB

    k_pre <<<dim3(SCAN_BLOCKS + WB_BLOCKS), dim3(256), 0, stream>>>(
        x, bind, unbind, decay, xs, endv, wt);
    k_fix <<<dim3(256),   dim3(256), 0, stream>>>(endv, decay, xs);
    k_gemm<<<dim3(64, 8), dim3(256), 0, stream>>>(xs, wt, x, gate, out);
}

// Round 4
// 134.333 us; speedup vs baseline: 1.4416x; 1.4416x over previous
//
#include <hip/hip_runtime.h>
#include <hip/hip_bf16.h>

// Problem constants
constexpr int Dd = 1024;           // feature dim
constexpr int Tt = 2048;           // sequence length
constexpr int Bb = 4;              // batch
constexpr int Rr = Bb * Tt;        // GEMM rows = 8192
constexpr int NCH = 64;            // scan chunks
constexpr int CL  = 32;            // steps per chunk
constexpr int SCB = Bb * NCH;      // 256 scan blocks (one per (b,chunk))
constexpr int CBL = 64;            // c-reduction blocks
constexpr int WBL = 512;           // W-build blocks

typedef __attribute__((ext_vector_type(4))) float f32x4;
typedef __attribute__((ext_vector_type(8))) short bf16x8;

__device__ __forceinline__ float sigmoidf_(float v) {
    return 1.0f / (1.0f + expf(-v));
}

__device__ __forceinline__ short bf16bits(float f) {
    union { __hip_bfloat16 b; short s; } u;
    u.b = __float2bfloat16(f);
    return u.s;
}

__device__ __forceinline__ void async16(const void* g, void* l) {
    __builtin_amdgcn_global_load_lds(
        (const __attribute__((address_space(1))) unsigned int*)g,
        (__attribute__((address_space(3))) unsigned int*)l,
        16, 0, 0);
}

// ---------------------------------------------------------------------------
// Kernel A: blocks [0,256): endv[b][chunk][d] = chunk-local EMA end value,
//           float4 per thread (d4 = tid), 32 steps, 1KB/wave loads.
//           blocks [256,320): c[n] = sum_m unbind[m]*bind[(m+n)%D],
//           16 threads per n (seg-partitioned, broadcast-friendly LDS).
// grid 320 x 256
__global__ void k_endc(const float* __restrict__ x,
                       const float* __restrict__ bind,
                       const float* __restrict__ unbind,
                       const float* __restrict__ decay,
                       float* __restrict__ endv,
                       float* __restrict__ c) {
    __shared__ float sb[Dd];
    __shared__ float su[Dd];
    __shared__ float sp[256];

    const int tid = threadIdx.x;
    if (blockIdx.x < SCB) {
        const int chunk = blockIdx.x & (NCH - 1);
        const int b = blockIdx.x >> 6;
        const float dd = sigmoidf_(decay[0]);
        const size_t base = ((size_t)b * Tt + (size_t)chunk * CL) * Dd + tid * 4;
        f32x4 e = (f32x4){0.f, 0.f, 0.f, 0.f};
        #pragma unroll 8
        for (int t = 0; t < CL; ++t) {
            f32x4 v = *(const f32x4*)&x[base + (size_t)t * Dd];
            e = dd * e + v;
        }
        *(f32x4*)&endv[((size_t)b * NCH + chunk) * Dd + tid * 4] = e;
    } else {
        // c-reduction: block handles 16 n-values; thread = (n_loc, seg)
        for (int j = tid; j < Dd; j += 256) { sb[j] = bind[j]; su[j] = unbind[j]; }
        __syncthreads();
        const int n_loc = tid >> 4;
        const int seg = tid & 15;
        const int n = (int)(blockIdx.x - SCB) * 16 + n_loc;
        float acc = 0.f;
        #pragma unroll 8
        for (int i = 0; i < 64; ++i) {
            const int m = i * 16 + seg;          // su: broadcast groups; sb: addr dep only on seg+n_loc
            acc = fmaf(su[m], sb[(m + n) & (Dd - 1)], acc);
        }
        sp[tid] = acc;
        __syncthreads();
        if (tid < 16) {
            float s = 0.f;
            #pragma unroll
            for (int j = 0; j < 16; ++j) s += sp[tid * 16 + j];
            c[(int)(blockIdx.x - SCB) * 16 + tid] = s;
        }
    }
}

// ---------------------------------------------------------------------------
// Kernel B: blocks [0,256): full scan with carry injected, write bf16 xs once.
//           carry recombined per-thread from endv (L2-hot, <=63 steps).
//           blocks [256,768): Wt[n][k] = bf16(c[(n-k) mod D]) from global c.
// grid 768 x 256
__global__ void k_scanw(const float* __restrict__ x,
                        const float* __restrict__ c,
                        const float* __restrict__ decay,
                        const float* __restrict__ endv,
                        __hip_bfloat16* __restrict__ xs,
                        __hip_bfloat16* __restrict__ wt) {
    const int tid = threadIdx.x;
    if (blockIdx.x < SCB) {
        const int chunk = blockIdx.x & (NCH - 1);
        const int b = blockIdx.x >> 6;
        const float dd = sigmoidf_(decay[0]);
        const float dL = powf(dd, (float)CL);
        // carry for this chunk: run over preceding chunks' endvals (fp32)
        f32x4 h = (f32x4){0.f, 0.f, 0.f, 0.f};
        const float* ep = endv + ((size_t)b * NCH) * Dd + tid * 4;
        for (int cc = 0; cc < chunk; ++cc)
            h = dL * h + *(const f32x4*)&ep[(size_t)cc * Dd];
        // scan 32 steps, write bf16x4 (8B/lane)
        const size_t base = ((size_t)b * Tt + (size_t)chunk * CL) * Dd + tid * 4;
        #pragma unroll 8
        for (int t = 0; t < CL; ++t) {
            f32x4 v = *(const f32x4*)&x[base + (size_t)t * Dd];
            h = dd * h + v;
            short4 o;
            o.x = bf16bits(h[0]); o.y = bf16bits(h[1]);
            o.z = bf16bits(h[2]); o.w = bf16bits(h[3]);
            *(short4*)&xs[base + (size_t)t * Dd] = o;
        }
    } else {
        // W-build: 8 outputs per thread from 4KB L2-hot c
        const int idx8 = (int)(blockIdx.x - SCB) * 256 + tid;
        const int n = idx8 >> 7;
        const int k0 = (idx8 & 127) * 8;
        bf16x8 v;
        #pragma unroll
        for (int j = 0; j < 8; ++j)
            v[j] = bf16bits(c[(n - (k0 + j)) & (Dd - 1)]);
        *(bf16x8*)&wt[(size_t)n * Dd + k0] = v;
    }
}

// ---------------------------------------------------------------------------
// Kernel C: out[r][n] = x[r][n] + gate * sum_k xs[r][k] * Wt[n][k]
// 128x128 tile, BK=32, 4 waves 2x2, 16x16x32 bf16 MFMA, async LDS staging.
// grid (64, 8) x 256
__global__ __launch_bounds__(256) void k_gemm(
    const __hip_bfloat16* __restrict__ A,   // [R][D] bf16 (scanned x)
    const __hip_bfloat16* __restrict__ Wt,  // [D][D] bf16, Wt[n][k]
    const float* __restrict__ x,            // [R][D] fp32
    const float* __restrict__ gate,         // [1]
    float* __restrict__ out)                // [R][D] fp32
{
    __shared__ __align__(16) __hip_bfloat16 sA[128 * 32];
    __shared__ __align__(16) __hip_bfloat16 sB[128 * 32];

    const int tid = threadIdx.x;
    const int wave = tid >> 6;
    const int lane = tid & 63;
    const int tile_m = blockIdx.x * 128;
    const int tile_n = blockIdx.y * 128;
    const int wm = (wave & 1) * 64;
    const int wn = (wave >> 1) * 64;

    f32x4 acc[4][4];
    #pragma unroll
    for (int i = 0; i < 4; ++i)
        #pragma unroll
        for (int j = 0; j < 4; ++j)
            acc[i][j] = (f32x4){0.f, 0.f, 0.f, 0.f};

    const int srow = lane >> 2;
    const int skk  = (lane & 3) * 8;
    const int fr = lane & 15;
    const int fk = (lane >> 4) * 8;

    for (int k0 = 0; k0 < Dd; k0 += 32) {
        __syncthreads();
        #pragma unroll
        for (int j = 0; j < 2; ++j) {
            const int row = wave * 32 + j * 16;  // wave-uniform
            async16(A  + (size_t)(tile_m + row + srow) * Dd + k0 + skk, &sA[row * 32]);
            async16(Wt + (size_t)(tile_n + row + srow) * Dd + k0 + skk, &sB[row * 32]);
        }
        __syncthreads();

        bf16x8 af[4], bfr[4];
        #pragma unroll
        for (int mt = 0; mt < 4; ++mt)
            af[mt] = *(const bf16x8*)&sA[(wm + mt * 16 + fr) * 32 + fk];
        #pragma unroll
        for (int nt = 0; nt < 4; ++nt)
            bfr[nt] = *(const bf16x8*)&sB[(wn + nt * 16 + fr) * 32 + fk];

        #pragma unroll
        for (int mt = 0; mt < 4; ++mt)
            #pragma unroll
            for (int nt = 0; nt < 4; ++nt)
                acc[mt][nt] = __builtin_amdgcn_mfma_f32_16x16x32_bf16(
                    af[mt], bfr[nt], acc[mt][nt], 0, 0, 0);
    }

    const float g = gate[0];
    #pragma unroll
    for (int mt = 0; mt < 4; ++mt) {
        const int row0 = tile_m + wm + mt * 16 + (lane >> 4) * 4;
        #pragma unroll
        for (int nt = 0; nt < 4; ++nt) {
            const int col = tile_n + wn + nt * 16 + (lane & 15);
            #pragma unroll
            for (int gg = 0; gg < 4; ++gg) {
                const size_t off = (size_t)(row0 + gg) * Dd + col;
                out[off] = fmaf(g, acc[mt][nt][gg], x[off]);
            }
        }
    }
}

// ---------------------------------------------------------------------------
extern "C" void kernel_launch(void* const* d_in, const int* in_sizes, int n_in,
                              void* d_out, int out_size, void* d_ws, size_t ws_size,
                              hipStream_t stream) {
    const float* x      = (const float*)d_in[0];
    const float* bind   = (const float*)d_in[1];
    const float* unbind = (const float*)d_in[2];
    const float* gate   = (const float*)d_in[3];
    const float* decay  = (const float*)d_in[4];
    float* out = (float*)d_out;

    // workspace layout (~19.8 MB)
    char* ws = (char*)d_ws;
    __hip_bfloat16* wt = (__hip_bfloat16*)ws;                              // 2 MB
    __hip_bfloat16* xs = (__hip_bfloat16*)(ws + (size_t)Dd * Dd * 2);      // 16.8 MB
    float* endv = (float*)(ws + (size_t)Dd * Dd * 2 + (size_t)Rr * Dd * 2);// 1 MB
    float* c    = endv + (size_t)Bb * NCH * Dd;                            // 4 KB

    k_endc <<<dim3(SCB + CBL), dim3(256), 0, stream>>>(x, bind, unbind, decay, endv, c);
    k_scanw<<<dim3(SCB + WBL), dim3(256), 0, stream>>>(x, c, decay, endv, xs, wt);
    k_gemm <<<dim3(64, 8),     dim3(256), 0, stream>>>(xs, wt, x, gate, out);
}